// Round 1
// 452.807 us; speedup vs baseline: 1.0165x; 1.0165x over previous
//
#include <hip/hip_runtime.h>

// Fastfood transform: out = (1/n) * H (G .* P( H (B .* x) )) per row,
// n = 16384, 4096 rows, fp32. Both 1/sqrt(n) folded into one 1/n at the end.
//
// One block (512 threads, 8 waves) per row; 64 KiB LDS = the row; 2 blocks/CU.
//
// Element index bits: i = [A(3)|Bb(3)|C(3)|D(3)|cl(2)], f4 index j = i>>2.
// Thread id t = [tu(3)|tv(3)|tw(3)] (tu = wave). Entry: r[m] = f4 at
// j = m*512 + t  ->  (A=m slot, Bb=tu, C=tv, D=tw).
//
// FWHT_16384 = pass1 (cl+A, 5 bits in regs)
//            + round1: WAVE-LOCAL swap slots<->tw   (butterfly D)   no barrier
//            + round2: WAVE-LOCAL swap slots<->tv   (butterfly C)   no barrier
//            + round3: cross-wave rotation, slots<-Bb, A->tu-pos    2 barriers
// Exit: r[m] = f4 at j = tu*512 + m*64 + tv*8 + tw (natural/coalesced), same
// as the previous rotate-only version, so natural write / gather / store are
// unchanged. Barriers per kernel: 14 -> 5.
//
// Wave-local rounds touch only this wave's 8 KiB region (base tu*512 f4);
// same-wave DS ops are in-order and the compiler inserts lgkmcnt waits, so
// no __syncthreads() is needed there.
//
// Bank-group check (f4 units, group = addr&7; every 8 consecutive lanes
// (fixed tv, tw=0..7) must hit 8 distinct groups):
//  r1 W: tv*64+m*8+(tw^m)        grp=tw^m   OK
//  r1 R: tv*64+tw*8+(m^tw)       grp=m^tw   OK
//  r2 W: tv*64+m*8+tw            grp=tw     OK
//  r2 R: m*64+tv*8+tw            grp=tw     OK
//  r3 W: tu*512+tw*64+m*8+(tv^tw) grp=tv^tw OK   (own region)
//  r3 R: m*512+tu*64+tv*8+(tw^tu) grp=tw^tu OK   (tu uniform per wave)
//  natural W / store: tu*512+m*64+tv*8+tw   grp=tw OK

#define L_N 16384

__device__ __forceinline__ float4 f4add(float4 a, float4 b) {
    return make_float4(a.x + b.x, a.y + b.y, a.z + b.z, a.w + b.w);
}
__device__ __forceinline__ float4 f4sub(float4 a, float4 b) {
    return make_float4(a.x - b.x, a.y - b.y, a.z - b.z, a.w - b.w);
}

// FWHT_4 within one float4 (the cl bits)
__device__ __forceinline__ void fwht4_inner(float4& a) {
    float s0 = a.x + a.y, d0 = a.x - a.y;
    float s1 = a.z + a.w, d1 = a.z - a.w;
    a.x = s0 + s1; a.y = d0 + d1; a.z = s0 - s1; a.w = d0 - d1;
}

// FWHT_8 across the 8 float4 slots (vectorized over the 4 inner lanes)
__device__ __forceinline__ void fwht8_vec(float4 v[8]) {
    #pragma unroll
    for (int s = 1; s < 8; s <<= 1) {
        #pragma unroll
        for (int k = 0; k < 8; ++k) {
            if ((k & s) == 0) {
                float4 a = v[k], b = v[k + s];
                v[k]     = f4add(a, b);
                v[k + s] = f4sub(a, b);
            }
        }
    }
}

// Full FWHT_16384 (unnormalized). Entry: r[m] = f4 at j = m*512 + t.
// Exit: r[m] = f4 at j = tu*512 + m*64 + tv*8 + tw.
// Contains ONE internal __syncthreads (before the cross-wave read).
// No trailing sync; caller must sync before reusing lds4 (WAR vs r3 reads).
__device__ __forceinline__ void fwht16384(float4 (&r)[8], float4* lds4,
                                          int tu, int tv, int tw) {
    // pass1: cl (2 bits) + A (3 slot bits)
    #pragma unroll
    for (int k = 0; k < 8; ++k) fwht4_inner(r[k]);
    fwht8_vec(r);

    float4* w = lds4 + tu * 512;   // this wave's private 8 KiB region

    // round1 (wave-local): slots<->tw. After: r[m] = elem(A=tw, C=tv, D=m)
    #pragma unroll
    for (int m = 0; m < 8; ++m) w[tv * 64 + m * 8 + (tw ^ m)] = r[m];
    #pragma unroll
    for (int m = 0; m < 8; ++m) r[m] = w[tv * 64 + tw * 8 + (m ^ tw)];
    fwht8_vec(r);          // D

    // round2 (wave-local): slots<->tv. After: r[m] = elem(A=tw, C=m, D=tv)
    #pragma unroll
    for (int m = 0; m < 8; ++m) w[tv * 64 + m * 8 + tw] = r[m];
    #pragma unroll
    for (int m = 0; m < 8; ++m) r[m] = w[m * 64 + tv * 8 + tw];
    fwht8_vec(r);          // C

    // round3 (cross-wave rotation): write own region, read everywhere.
    // After: r[m] = elem(A=tu, Bb=m, C=tv, D=tw)  -> natural exit layout.
    #pragma unroll
    for (int m = 0; m < 8; ++m) w[tw * 64 + m * 8 + (tv ^ tw)] = r[m];
    __syncthreads();
    #pragma unroll
    for (int m = 0; m < 8; ++m) r[m] = lds4[m * 512 + tu * 64 + tv * 8 + (tw ^ tu)];
    fwht8_vec(r);          // Bb
}

extern "C" __global__ void __launch_bounds__(512, 4)
fastfood_kernel(const float* __restrict__ x,
                const float* __restrict__ Bv,
                const float* __restrict__ Gv,
                const int*   __restrict__ Pi,
                float* __restrict__ out)
{
    __shared__ float4 lds4[L_N / 4];          // 64 KiB, exactly one row
    float* lds = (float*)lds4;

    const int t  = threadIdx.x;
    const int tu = t >> 6, tv = (t >> 3) & 7, tw = t & 7;
    const long row = blockIdx.x;

    const float4* x4 = (const float4*)(x + row * (long)L_N);
    const float4* b4 = (const float4*)Bv;
    float4 r[8];

    // load row (coalesced: per slot, lanes consecutive), fold in B
    #pragma unroll
    for (int m = 0; m < 8; ++m) {
        float4 a = x4[m * 512 + t];
        float4 b = b4[m * 512 + t];
        r[m] = make_float4(a.x * b.x, a.y * b.y, a.z * b.z, a.w * b.w);
    }

    // ================= FWHT #1 =================
    fwht16384(r, lds4, tu, tv, tw);
    __syncthreads();   // all round3 reads done before natural write (WAR)

    // natural layout write for the permutation gather (own region, grp=tw)
    #pragma unroll
    for (int m = 0; m < 8; ++m) lds4[tu * 512 + m * 64 + tv * 8 + tw] = r[m];
    __syncthreads();

    // permutation + G: thread owns f4 index j = k*512 + t (coalesced Pi/G);
    // result directly matches FWHT#2 entry layout (slots = A).
    {
        const int4*   p4 = (const int4*)Pi;
        const float4* g4 = (const float4*)Gv;
        #pragma unroll
        for (int k = 0; k < 8; ++k) {
            int4   p = p4[k * 512 + t];
            float4 g = g4[k * 512 + t];
            r[k] = make_float4(lds[p.x] * g.x, lds[p.y] * g.y,
                               lds[p.z] * g.z, lds[p.w] * g.w);
        }
    }
    __syncthreads();   // all gather reads done before FWHT#2 writes LDS

    // ================= FWHT #2 =================
    fwht16384(r, lds4, tu, tv, tw);

    // store, both normalizations folded; coalesced per slot
    const float sc = 1.0f / (float)L_N;
    float4* o4 = (float4*)(out + row * (long)L_N);
    #pragma unroll
    for (int m = 0; m < 8; ++m) {
        float4 a = r[m];
        o4[tu * 512 + m * 64 + tv * 8 + tw] =
            make_float4(a.x * sc, a.y * sc, a.z * sc, a.w * sc);
    }
}

extern "C" void kernel_launch(void* const* d_in, const int* in_sizes, int n_in,
                              void* d_out, int out_size, void* d_ws, size_t ws_size,
                              hipStream_t stream) {
    const float* x  = (const float*)d_in[0];
    const float* B  = (const float*)d_in[1];
    const float* G  = (const float*)d_in[2];
    const int*   Pi = (const int*)d_in[3];
    float* out = (float*)d_out;

    const int rows = in_sizes[0] / L_N;       // 4096
    fastfood_kernel<<<rows, 512, 0, stream>>>(x, B, G, Pi, out);
}